// Round 1
// baseline (420.632 us; speedup 1.0000x reference)
//
#include <hip/hip_runtime.h>
#include <hip/hip_bf16.h>

// Problem constants (T,K,E,H,I) = (1024, 2, 8, 2048, 1024)
#define T_TOK 1024
#define KSEL  2
#define NEXP  8
#define HDIM  2048
#define IDIM  1024
#define TK    (T_TOK * KSEL)   // 2048 (token, slot) pairs

// LDS row stride in bf16 elements: 32 payload + 8 pad = 80 bytes.
// 80 % 16 == 0 (ds_read_b128 aligned); 20-bank stride -> 2-way conflicts only (free).
#define RS 40

typedef float  f32x4  __attribute__((ext_vector_type(4)));
typedef __bf16 bf16x8 __attribute__((ext_vector_type(8)));

__device__ __forceinline__ unsigned short f2bf(float f) {
    union { float f; unsigned u; } v; v.f = f;
    unsigned r = (v.u >> 16) & 1u;               // round-to-nearest-even
    return (unsigned short)((v.u + 0x7fffu + r) >> 16);
}

// ---------------------------------------------------------------------------
// Kernel 1: bucket the 2048 (t,k) pairs by expert (counting sort, 1 block).
// meta[0..7] = count per expert, meta[8..15] = segment start.
// pairs[] holds idx = t*K + k (== output row index) grouped by expert.
// ---------------------------------------------------------------------------
__global__ void build_pairs(const int* __restrict__ sel, int* __restrict__ meta,
                            int* __restrict__ pairs) {
    __shared__ int lcnt[NEXP], lstart[NEXP], lfill[NEXP];
    const int tid = threadIdx.x;
    if (tid < NEXP) { lcnt[tid] = 0; lfill[tid] = 0; }
    __syncthreads();
    for (int idx = tid; idx < TK; idx += 256) atomicAdd(&lcnt[sel[idx]], 1);
    __syncthreads();
    if (tid == 0) {
        int s = 0;
        for (int e = 0; e < NEXP; ++e) { lstart[e] = s; s += lcnt[e]; }
    }
    __syncthreads();
    for (int idx = tid; idx < TK; idx += 256) {
        int e = sel[idx];
        int pos = lstart[e] + atomicAdd(&lfill[e], 1);
        pairs[pos] = idx;
    }
    if (tid < NEXP) { meta[tid] = lcnt[tid]; meta[NEXP + tid] = lstart[tid]; }
}

// ---------------------------------------------------------------------------
// Kernel 2: fused gate_up GEMM + SiLU*up -> bf16 intermediate (packed rows).
// Block tile: 128 packed rows x 64 intermediate cols. Loads BOTH the gate
// weight rows [n0, n0+64) and up rows [I+n0, I+n0+64) so silu(g)*u fuses in
// the epilogue. fp32 weights/activations converted to bf16 during staging.
// Grid: mt(16) x e(8) x nt(16); blocks with m0 >= count[e] exit immediately.
// ---------------------------------------------------------------------------
__global__ __launch_bounds__(256) void gemm1_gateup(
    const float* __restrict__ hidden, const float* __restrict__ gup,
    const int* __restrict__ meta, const int* __restrict__ pairs,
    unsigned short* __restrict__ inter)
{
    __shared__ __align__(16) unsigned short As[128 * RS];
    __shared__ __align__(16) unsigned short Bs[128 * RS];

    const int bx = blockIdx.x;
    const int nt = bx & 15, e = (bx >> 4) & 7, mt = bx >> 7;
    const int cnt = meta[e];
    const int m0 = mt * 128;
    if (m0 >= cnt) return;
    const int seg  = meta[8 + e];
    const int rows = min(128, cnt - m0);
    const int n0   = nt * 64;

    const int tid  = threadIdx.x;
    const int lane = tid & 63, wave = tid >> 6;
    const int quad = lane >> 4, l16 = lane & 15;
    const int wm = wave >> 1, wn = wave & 1;

    const float* __restrict__ Wb = gup + (size_t)e * (2 * IDIM * HDIM);

    // Staging: 256 threads cover 128 rows x 32 fp32; 8 threads/row, float4 each.
    const int srow = tid >> 3, scol = (tid & 7) * 4;
    const float* aptr[4]; const float* bptr[4]; bool aval[4];
    #pragma unroll
    for (int c = 0; c < 4; ++c) {
        int r = srow + c * 32;
        aval[c] = (r < rows);
        int tok = aval[c] ? (pairs[seg + m0 + r] >> 1) : 0;   // idx = t*2+k -> t
        aptr[c] = hidden + (size_t)tok * HDIM + scol;
        int wr = (r < 64) ? (n0 + r) : (IDIM + n0 + (r - 64)); // gate rows then up rows
        bptr[c] = Wb + (size_t)wr * HDIM + scol;
    }

    f32x4 accg[4][2], accu[4][2];
    const f32x4 zero = {0.f, 0.f, 0.f, 0.f};
    #pragma unroll
    for (int i = 0; i < 4; ++i)
        #pragma unroll
        for (int j = 0; j < 2; ++j) { accg[i][j] = zero; accu[i][j] = zero; }

    for (int k0 = 0; k0 < HDIM; k0 += 32) {
        #pragma unroll
        for (int c = 0; c < 4; ++c) {
            int r = srow + c * 32;
            float4 av = aval[c] ? *(const float4*)(aptr[c] + k0) : make_float4(0.f,0.f,0.f,0.f);
            float4 bv = *(const float4*)(bptr[c] + k0);
            ushort4 a4, b4;
            a4.x = f2bf(av.x); a4.y = f2bf(av.y); a4.z = f2bf(av.z); a4.w = f2bf(av.w);
            b4.x = f2bf(bv.x); b4.y = f2bf(bv.y); b4.z = f2bf(bv.z); b4.w = f2bf(bv.w);
            *(ushort4*)&As[r * RS + scol] = a4;
            *(ushort4*)&Bs[r * RS + scol] = b4;
        }
        __syncthreads();

        bf16x8 af[4], bg[2], bu[2];
        const int kq = quad * 8;
        #pragma unroll
        for (int i = 0; i < 4; ++i)
            af[i] = *(const bf16x8*)&As[(wm * 64 + i * 16 + l16) * RS + kq];
        #pragma unroll
        for (int j = 0; j < 2; ++j) {
            bg[j] = *(const bf16x8*)&Bs[(wn * 32 + j * 16 + l16) * RS + kq];
            bu[j] = *(const bf16x8*)&Bs[(64 + wn * 32 + j * 16 + l16) * RS + kq];
        }
        #pragma unroll
        for (int i = 0; i < 4; ++i)
            #pragma unroll
            for (int j = 0; j < 2; ++j) {
                accg[i][j] = __builtin_amdgcn_mfma_f32_16x16x32_bf16(af[i], bg[j], accg[i][j], 0, 0, 0);
                accu[i][j] = __builtin_amdgcn_mfma_f32_16x16x32_bf16(af[i], bu[j], accu[i][j], 0, 0, 0);
            }
        __syncthreads();
    }

    // Epilogue: inter[row][n] = silu(gate) * up, stored bf16.
    #pragma unroll
    for (int i = 0; i < 4; ++i) {
        #pragma unroll
        for (int r = 0; r < 4; ++r) {
            int ml = wm * 64 + i * 16 + quad * 4 + r;
            if (ml < rows) {
                size_t orow = (size_t)(seg + m0 + ml) * IDIM;
                #pragma unroll
                for (int j = 0; j < 2; ++j) {
                    int n = n0 + wn * 32 + j * 16 + l16;
                    float g = accg[i][j][r], u = accu[i][j][r];
                    float s = g * (1.f / (1.f + __expf(-g)));
                    inter[orow + n] = f2bf(s * u);
                }
            }
        }
    }
}

// ---------------------------------------------------------------------------
// Kernel 3: down-proj GEMM. C[p, n] = sum_m inter[p,m] * down[e][n][m],
// output scattered to out[pairs[p]] (fp32). Block tile 128 x 128, K = 1024.
// ---------------------------------------------------------------------------
__global__ __launch_bounds__(256) void gemm2_down(
    const unsigned short* __restrict__ inter, const float* __restrict__ down,
    const int* __restrict__ meta, const int* __restrict__ pairs,
    float* __restrict__ out)
{
    __shared__ __align__(16) unsigned short As[128 * RS];
    __shared__ __align__(16) unsigned short Bs[128 * RS];

    const int bx = blockIdx.x;
    const int nt = bx & 15, e = (bx >> 4) & 7, mt = bx >> 7;
    const int cnt = meta[e];
    const int m0 = mt * 128;
    if (m0 >= cnt) return;
    const int seg  = meta[8 + e];
    const int rows = min(128, cnt - m0);
    const int n0   = nt * 128;

    const int tid  = threadIdx.x;
    const int lane = tid & 63, wave = tid >> 6;
    const int quad = lane >> 4, l16 = lane & 15;
    const int wm = wave >> 1, wn = wave & 1;

    const float* __restrict__ Db = down + (size_t)e * (HDIM * IDIM);

    // B staging: 128 weight rows x 32 fp32 (8 threads/row).
    const int srow = tid >> 3, scol = (tid & 7) * 4;
    const float* bptr[4];
    #pragma unroll
    for (int c = 0; c < 4; ++c) {
        int r = srow + c * 32;
        bptr[c] = Db + (size_t)(n0 + r) * IDIM + scol;
    }
    // A staging: 128 rows x 32 bf16 = 512 x 16B chunks; 2 chunks/thread.
    const unsigned short* iptr[2]; bool aval[2]; int aofs[2];
    #pragma unroll
    for (int c = 0; c < 2; ++c) {
        int id = tid + c * 256;
        int r = id >> 2, ko = (id & 3) * 8;
        aval[c] = (r < rows);
        iptr[c] = inter + (size_t)(seg + m0 + (aval[c] ? r : 0)) * IDIM + ko;
        aofs[c] = r * RS + ko;
    }

    f32x4 acc[4][4];
    const f32x4 zero = {0.f, 0.f, 0.f, 0.f};
    #pragma unroll
    for (int i = 0; i < 4; ++i)
        #pragma unroll
        for (int j = 0; j < 4; ++j) acc[i][j] = zero;

    for (int k0 = 0; k0 < IDIM; k0 += 32) {
        #pragma unroll
        for (int c = 0; c < 2; ++c) {
            uint4 v = aval[c] ? *(const uint4*)(iptr[c] + k0) : make_uint4(0u,0u,0u,0u);
            *(uint4*)&As[aofs[c]] = v;
        }
        #pragma unroll
        for (int c = 0; c < 4; ++c) {
            int r = srow + c * 32;
            float4 bv = *(const float4*)(bptr[c] + k0);
            ushort4 b4;
            b4.x = f2bf(bv.x); b4.y = f2bf(bv.y); b4.z = f2bf(bv.z); b4.w = f2bf(bv.w);
            *(ushort4*)&Bs[r * RS + scol] = b4;
        }
        __syncthreads();

        bf16x8 af[4], bf[4];
        const int kq = quad * 8;
        #pragma unroll
        for (int i = 0; i < 4; ++i)
            af[i] = *(const bf16x8*)&As[(wm * 64 + i * 16 + l16) * RS + kq];
        #pragma unroll
        for (int j = 0; j < 4; ++j)
            bf[j] = *(const bf16x8*)&Bs[(wn * 64 + j * 16 + l16) * RS + kq];
        #pragma unroll
        for (int i = 0; i < 4; ++i)
            #pragma unroll
            for (int j = 0; j < 4; ++j)
                acc[i][j] = __builtin_amdgcn_mfma_f32_16x16x32_bf16(af[i], bf[j], acc[i][j], 0, 0, 0);
        __syncthreads();
    }

    #pragma unroll
    for (int i = 0; i < 4; ++i) {
        #pragma unroll
        for (int r = 0; r < 4; ++r) {
            int ml = wm * 64 + i * 16 + quad * 4 + r;
            if (ml < rows) {
                int p = pairs[seg + m0 + ml];               // == t*K + k = output row
                size_t ob = (size_t)p * HDIM + n0 + wn * 64 + l16;
                #pragma unroll
                for (int j = 0; j < 4; ++j)
                    out[ob + j * 16] = acc[i][j][r];
            }
        }
    }
}

// ---------------------------------------------------------------------------
extern "C" void kernel_launch(void* const* d_in, const int* in_sizes, int n_in,
                              void* d_out, int out_size, void* d_ws, size_t ws_size,
                              hipStream_t stream) {
    const float* hidden = (const float*)d_in[0];   // (T, H) fp32
    const int*   sel    = (const int*)  d_in[1];   // (T, K) int32
    const float* gup    = (const float*)d_in[2];   // (E, 2I, H) fp32
    const float* down   = (const float*)d_in[3];   // (E, H, I) fp32
    float* out = (float*)d_out;                    // (T, K, H) fp32

    int* meta  = (int*)d_ws;                       // 16 ints: cnt[8], start[8]
    int* pairs = meta + 16;                        // 2048 ints
    unsigned short* inter = (unsigned short*)((char*)d_ws + 16384); // 2048 x 1024 bf16 (4 MB)

    build_pairs<<<1, 256, 0, stream>>>(sel, meta, pairs);
    // grid: mt(16) x e(8) x nt(16) = 2048 blocks; inactive tiles exit fast.
    gemm1_gateup<<<2048, 256, 0, stream>>>(hidden, gup, meta, pairs, inter);
    gemm2_down  <<<2048, 256, 0, stream>>>(inter, down, meta, pairs, out);
}

// Round 2
// 391.773 us; speedup vs baseline: 1.0737x; 1.0737x over previous
//
#include <hip/hip_runtime.h>
#include <hip/hip_bf16.h>

// Problem constants (T,K,E,H,I) = (1024, 2, 8, 2048, 1024)
#define T_TOK 1024
#define KSEL  2
#define NEXP  8
#define HDIM  2048
#define IDIM  1024
#define TK    (T_TOK * KSEL)   // 2048 (token, slot) pairs

// LDS row stride in bf16 elements: 32 payload + 8 pad = 80 bytes.
#define RS 40

typedef float  f32x4  __attribute__((ext_vector_type(4)));
typedef __bf16 bf16x8 __attribute__((ext_vector_type(8)));

__device__ __forceinline__ unsigned short f2bf(float f) {
    union { float f; unsigned u; } v; v.f = f;
    unsigned r = (v.u >> 16) & 1u;               // round-to-nearest-even
    return (unsigned short)((v.u + 0x7fffu + r) >> 16);
}

// ---------------------------------------------------------------------------
// Kernel 1: bucket the 2048 (t,k) pairs by expert (counting sort, 1 block).
// ---------------------------------------------------------------------------
__global__ void build_pairs(const int* __restrict__ sel, int* __restrict__ meta,
                            int* __restrict__ pairs) {
    __shared__ int lcnt[NEXP], lstart[NEXP], lfill[NEXP];
    const int tid = threadIdx.x;
    if (tid < NEXP) { lcnt[tid] = 0; lfill[tid] = 0; }
    __syncthreads();
    for (int idx = tid; idx < TK; idx += 256) atomicAdd(&lcnt[sel[idx]], 1);
    __syncthreads();
    if (tid == 0) {
        int s = 0;
        for (int e = 0; e < NEXP; ++e) { lstart[e] = s; s += lcnt[e]; }
    }
    __syncthreads();
    for (int idx = tid; idx < TK; idx += 256) {
        int e = sel[idx];
        int pos = lstart[e] + atomicAdd(&lfill[e], 1);
        pairs[pos] = idx;
    }
    if (tid < NEXP) { meta[tid] = lcnt[tid]; meta[NEXP + tid] = lstart[tid]; }
}

// ---------------------------------------------------------------------------
// Kernel 2: gate_up GEMM + SiLU*up -> bf16 intermediate.
// M-tile 64 packed rows x 64 inter cols (= 128 weight rows: 64 gate + 64 up).
// Double-buffered LDS, one barrier per K-slab: loads for slab k issue before
// the MFMAs on slab k-1, so global latency overlaps compute.
// Grid: mt(32) x e(8) x nt(16) = 4096; ~512 blocks active (2/CU).
// ---------------------------------------------------------------------------
__global__ __launch_bounds__(256) void gemm1_gateup(
    const float* __restrict__ hidden, const float* __restrict__ gup,
    const int* __restrict__ meta, const int* __restrict__ pairs,
    unsigned short* __restrict__ inter)
{
    __shared__ __align__(16) unsigned short As[2][64 * RS];
    __shared__ __align__(16) unsigned short Bs[2][128 * RS];

    const int bx = blockIdx.x;
    const int nt = bx & 15, e = (bx >> 4) & 7, mt = bx >> 7;
    const int cnt = meta[e];
    const int m0 = mt * 64;
    if (m0 >= cnt) return;
    const int seg  = meta[8 + e];
    const int rows = min(64, cnt - m0);
    const int n0   = nt * 64;

    const int tid  = threadIdx.x;
    const int lane = tid & 63, wave = tid >> 6;
    const int quad = lane >> 4, l16 = lane & 15;
    const int wm = wave >> 1, wn = wave & 1;

    const float* __restrict__ Wb = gup + (size_t)e * (2 * IDIM * HDIM);

    // A staging: 64 rows x 32 fp32 = 512 float4 slots; 2 per thread.
    const float* aptr[2]; bool aval[2]; int aofs[2];
    #pragma unroll
    for (int c = 0; c < 2; ++c) {
        int id = tid + c * 256;
        int r = id >> 3, col = (id & 7) * 4;
        aval[c] = (r < rows);
        int tok = aval[c] ? (pairs[seg + m0 + r] >> 1) : 0;
        aptr[c] = hidden + (size_t)tok * HDIM + col;
        aofs[c] = r * RS + col;
    }
    // B staging: 128 weight rows x 32 fp32 = 1024 float4 slots; 4 per thread.
    const float* bptr[4]; int bofs[4];
    #pragma unroll
    for (int c = 0; c < 4; ++c) {
        int id = tid + c * 256;
        int r = id >> 3, col = (id & 7) * 4;
        int wr = (r < 64) ? (n0 + r) : (IDIM + n0 + (r - 64));
        bptr[c] = Wb + (size_t)wr * HDIM + col;
        bofs[c] = r * RS + col;
    }

    f32x4 accg[2][2], accu[2][2];
    const f32x4 zero = {0.f, 0.f, 0.f, 0.f};
    #pragma unroll
    for (int i = 0; i < 2; ++i)
        #pragma unroll
        for (int j = 0; j < 2; ++j) { accg[i][j] = zero; accu[i][j] = zero; }

    auto store_slab = [&](int buf, const float4 (&av)[2], const float4 (&bv)[4]) {
        #pragma unroll
        for (int c = 0; c < 2; ++c) {
            ushort4 a4;
            a4.x = f2bf(av[c].x); a4.y = f2bf(av[c].y);
            a4.z = f2bf(av[c].z); a4.w = f2bf(av[c].w);
            *(ushort4*)&As[buf][aofs[c]] = a4;
        }
        #pragma unroll
        for (int c = 0; c < 4; ++c) {
            ushort4 b4;
            b4.x = f2bf(bv[c].x); b4.y = f2bf(bv[c].y);
            b4.z = f2bf(bv[c].z); b4.w = f2bf(bv[c].w);
            *(ushort4*)&Bs[buf][bofs[c]] = b4;
        }
    };
    auto compute = [&](int buf) {
        bf16x8 af[2], bg[2], bu[2];
        const int kq = quad * 8;
        #pragma unroll
        for (int i = 0; i < 2; ++i)
            af[i] = *(const bf16x8*)&As[buf][(wm * 32 + i * 16 + l16) * RS + kq];
        #pragma unroll
        for (int j = 0; j < 2; ++j) {
            bg[j] = *(const bf16x8*)&Bs[buf][(wn * 32 + j * 16 + l16) * RS + kq];
            bu[j] = *(const bf16x8*)&Bs[buf][(64 + wn * 32 + j * 16 + l16) * RS + kq];
        }
        #pragma unroll
        for (int i = 0; i < 2; ++i)
            #pragma unroll
            for (int j = 0; j < 2; ++j) {
                accg[i][j] = __builtin_amdgcn_mfma_f32_16x16x32_bf16(af[i], bg[j], accg[i][j], 0, 0, 0);
                accu[i][j] = __builtin_amdgcn_mfma_f32_16x16x32_bf16(af[i], bu[j], accu[i][j], 0, 0, 0);
            }
    };

    const float4 z4 = make_float4(0.f, 0.f, 0.f, 0.f);
    // Prologue: slab 0 into buf 0.
    {
        float4 av[2], bv[4];
        #pragma unroll
        for (int c = 0; c < 2; ++c) av[c] = aval[c] ? *(const float4*)(aptr[c]) : z4;
        #pragma unroll
        for (int c = 0; c < 4; ++c) bv[c] = *(const float4*)(bptr[c]);
        store_slab(0, av, bv);
    }
    __syncthreads();

    const int NK = HDIM / 32;   // 64
    for (int k = 1; k < NK; ++k) {
        const int k0 = k * 32;
        float4 av[2], bv[4];
        #pragma unroll
        for (int c = 0; c < 2; ++c) av[c] = aval[c] ? *(const float4*)(aptr[c] + k0) : z4;
        #pragma unroll
        for (int c = 0; c < 4; ++c) bv[c] = *(const float4*)(bptr[c] + k0);
        compute((k - 1) & 1);          // overlaps the loads above
        store_slab(k & 1, av, bv);     // vmcnt drain lands here, after MFMA issue
        __syncthreads();
    }
    compute((NK - 1) & 1);

    // Epilogue: inter[row][n] = silu(gate) * up, bf16.
    #pragma unroll
    for (int i = 0; i < 2; ++i) {
        #pragma unroll
        for (int r = 0; r < 4; ++r) {
            int ml = wm * 32 + i * 16 + quad * 4 + r;
            if (ml < rows) {
                size_t orow = (size_t)(seg + m0 + ml) * IDIM;
                #pragma unroll
                for (int j = 0; j < 2; ++j) {
                    int n = n0 + wn * 32 + j * 16 + l16;
                    float g = accg[i][j][r], u = accu[i][j][r];
                    float s = g * (1.f / (1.f + __expf(-g)));
                    inter[orow + n] = f2bf(s * u);
                }
            }
        }
    }
}

// ---------------------------------------------------------------------------
// Kernel 3: down-proj GEMM, M-tile 64 x N-tile 128, double-buffered.
// Grid: mt(32) x e(8) x nt(16) = 4096; ~512 active.
// ---------------------------------------------------------------------------
__global__ __launch_bounds__(256) void gemm2_down(
    const unsigned short* __restrict__ inter, const float* __restrict__ down,
    const int* __restrict__ meta, const int* __restrict__ pairs,
    float* __restrict__ out)
{
    __shared__ __align__(16) unsigned short As[2][64 * RS];
    __shared__ __align__(16) unsigned short Bs[2][128 * RS];

    const int bx = blockIdx.x;
    const int nt = bx & 15, e = (bx >> 4) & 7, mt = bx >> 7;
    const int cnt = meta[e];
    const int m0 = mt * 64;
    if (m0 >= cnt) return;
    const int seg  = meta[8 + e];
    const int rows = min(64, cnt - m0);
    const int n0   = nt * 128;

    const int tid  = threadIdx.x;
    const int lane = tid & 63, wave = tid >> 6;
    const int quad = lane >> 4, l16 = lane & 15;
    const int wm = wave >> 1, wn = wave & 1;

    const float* __restrict__ Db = down + (size_t)e * (HDIM * IDIM);

    // A staging: 64 rows x 32 bf16 = 256 x 16B chunks; 1 per thread.
    const int ar = tid >> 2, ako = (tid & 3) * 8;
    const bool aval = (ar < rows);
    const unsigned short* iptr = inter + (size_t)(seg + m0 + (aval ? ar : 0)) * IDIM + ako;
    const int aofs = ar * RS + ako;

    // B staging: 128 weight rows x 32 fp32; 4 float4 per thread.
    const float* bptr[4]; int bofs[4];
    #pragma unroll
    for (int c = 0; c < 4; ++c) {
        int id = tid + c * 256;
        int r = id >> 3, col = (id & 7) * 4;
        bptr[c] = Db + (size_t)(n0 + r) * IDIM + col;
        bofs[c] = r * RS + col;
    }

    f32x4 acc[2][4];
    const f32x4 zero = {0.f, 0.f, 0.f, 0.f};
    #pragma unroll
    for (int i = 0; i < 2; ++i)
        #pragma unroll
        for (int j = 0; j < 4; ++j) acc[i][j] = zero;

    auto store_slab = [&](int buf, uint4 avv, const float4 (&bv)[4]) {
        *(uint4*)&As[buf][aofs] = avv;
        #pragma unroll
        for (int c = 0; c < 4; ++c) {
            ushort4 b4;
            b4.x = f2bf(bv[c].x); b4.y = f2bf(bv[c].y);
            b4.z = f2bf(bv[c].z); b4.w = f2bf(bv[c].w);
            *(ushort4*)&Bs[buf][bofs[c]] = b4;
        }
    };
    auto compute = [&](int buf) {
        bf16x8 af[2], bf[4];
        const int kq = quad * 8;
        #pragma unroll
        for (int i = 0; i < 2; ++i)
            af[i] = *(const bf16x8*)&As[buf][(wm * 32 + i * 16 + l16) * RS + kq];
        #pragma unroll
        for (int j = 0; j < 4; ++j)
            bf[j] = *(const bf16x8*)&Bs[buf][(wn * 64 + j * 16 + l16) * RS + kq];
        #pragma unroll
        for (int i = 0; i < 2; ++i)
            #pragma unroll
            for (int j = 0; j < 4; ++j)
                acc[i][j] = __builtin_amdgcn_mfma_f32_16x16x32_bf16(af[i], bf[j], acc[i][j], 0, 0, 0);
    };

    const uint4 zu4 = make_uint4(0u, 0u, 0u, 0u);
    const float4 z4f = make_float4(0.f, 0.f, 0.f, 0.f); (void)z4f;
    // Prologue
    {
        uint4 avv = aval ? *(const uint4*)(iptr) : zu4;
        float4 bv[4];
        #pragma unroll
        for (int c = 0; c < 4; ++c) bv[c] = *(const float4*)(bptr[c]);
        store_slab(0, avv, bv);
    }
    __syncthreads();

    const int NK = IDIM / 32;   // 32
    for (int k = 1; k < NK; ++k) {
        const int k0 = k * 32;
        uint4 avv = aval ? *(const uint4*)(iptr + k0) : zu4;
        float4 bv[4];
        #pragma unroll
        for (int c = 0; c < 4; ++c) bv[c] = *(const float4*)(bptr[c] + k0);
        compute((k - 1) & 1);
        store_slab(k & 1, avv, bv);
        __syncthreads();
    }
    compute((NK - 1) & 1);

    #pragma unroll
    for (int i = 0; i < 2; ++i) {
        #pragma unroll
        for (int r = 0; r < 4; ++r) {
            int ml = wm * 32 + i * 16 + quad * 4 + r;
            if (ml < rows) {
                int p = pairs[seg + m0 + ml];
                size_t ob = (size_t)p * HDIM + n0 + wn * 64 + l16;
                #pragma unroll
                for (int j = 0; j < 4; ++j)
                    out[ob + j * 16] = acc[i][j][r];
            }
        }
    }
}

// ---------------------------------------------------------------------------
extern "C" void kernel_launch(void* const* d_in, const int* in_sizes, int n_in,
                              void* d_out, int out_size, void* d_ws, size_t ws_size,
                              hipStream_t stream) {
    const float* hidden = (const float*)d_in[0];   // (T, H) fp32
    const int*   sel    = (const int*)  d_in[1];   // (T, K) int32
    const float* gup    = (const float*)d_in[2];   // (E, 2I, H) fp32
    const float* down   = (const float*)d_in[3];   // (E, H, I) fp32
    float* out = (float*)d_out;                    // (T, K, H) fp32

    int* meta  = (int*)d_ws;                       // 16 ints: cnt[8], start[8]
    int* pairs = meta + 16;                        // 2048 ints
    unsigned short* inter = (unsigned short*)((char*)d_ws + 16384); // 2048 x 1024 bf16 (4 MB)

    build_pairs<<<1, 256, 0, stream>>>(sel, meta, pairs);
    gemm1_gateup<<<4096, 256, 0, stream>>>(hidden, gup, meta, pairs, inter);
    gemm2_down  <<<4096, 256, 0, stream>>>(inter, down, meta, pairs, out);
}

// Round 3
// 338.994 us; speedup vs baseline: 1.2408x; 1.1557x over previous
//
#include <hip/hip_runtime.h>
#include <hip/hip_bf16.h>

// Problem constants (T,K,E,H,I) = (1024, 2, 8, 2048, 1024)
#define T_TOK 1024
#define KSEL  2
#define NEXP  8
#define HDIM  2048
#define IDIM  1024
#define TK    (T_TOK * KSEL)   // 2048 (token, slot) pairs

// LDS row stride in bf16 elements: 32 payload + 8 pad = 80 bytes (16B-aligned).
#define RS 40

typedef float  f32x4  __attribute__((ext_vector_type(4)));
typedef __bf16 bf16x8 __attribute__((ext_vector_type(8)));
typedef __bf16 bf16x2 __attribute__((ext_vector_type(2)));

__device__ __forceinline__ unsigned short f2bf(float f) {
    union { float f; unsigned u; } v; v.f = f;
    unsigned r = (v.u >> 16) & 1u;               // round-to-nearest-even
    return (unsigned short)((v.u + 0x7fffu + r) >> 16);
}

__device__ __forceinline__ unsigned pk2bf(float lo, float hi) {
#if __has_builtin(__builtin_amdgcn_cvt_pk_bf16_f32)
    bf16x2 v = __builtin_amdgcn_cvt_pk_bf16_f32(lo, hi);
    union { bf16x2 v; unsigned u; } c; c.v = v;
    return c.u;
#else
    return (unsigned)f2bf(lo) | ((unsigned)f2bf(hi) << 16);
#endif
}

__device__ __forceinline__ void st_bf4(unsigned short* dst, float4 v) {
    uint2 u;
    u.x = pk2bf(v.x, v.y);
    u.y = pk2bf(v.z, v.w);
    *(uint2*)dst = u;
}

// ---------------------------------------------------------------------------
// Kernel 1: bucket the 2048 (t,k) pairs by expert (counting sort, 1 block).
// ---------------------------------------------------------------------------
__global__ void build_pairs(const int* __restrict__ sel, int* __restrict__ meta,
                            int* __restrict__ pairs) {
    __shared__ int lcnt[NEXP], lstart[NEXP], lfill[NEXP];
    const int tid = threadIdx.x;
    if (tid < NEXP) { lcnt[tid] = 0; lfill[tid] = 0; }
    __syncthreads();
    for (int idx = tid; idx < TK; idx += 256) atomicAdd(&lcnt[sel[idx]], 1);
    __syncthreads();
    if (tid == 0) {
        int s = 0;
        for (int e = 0; e < NEXP; ++e) { lstart[e] = s; s += lcnt[e]; }
    }
    __syncthreads();
    for (int idx = tid; idx < TK; idx += 256) {
        int e = sel[idx];
        int pos = lstart[e] + atomicAdd(&lfill[e], 1);
        pairs[pos] = idx;
    }
    if (tid < NEXP) { meta[tid] = lcnt[tid]; meta[NEXP + tid] = lstart[tid]; }
}

// ---------------------------------------------------------------------------
// Kernel 2: gate_up GEMM + SiLU*up -> bf16 intermediate.
// Tile 64 packed rows x 64 inter cols (128 weight rows). Depth-3 pipeline:
// slab s: global->reg at iter s-3, reg->LDS at iter s-1, MFMA at iter s.
// ---------------------------------------------------------------------------
__global__ __launch_bounds__(256) void gemm1_gateup(
    const float* __restrict__ hidden, const float* __restrict__ gup,
    const int* __restrict__ meta, const int* __restrict__ pairs,
    unsigned short* __restrict__ inter)
{
    __shared__ __align__(16) unsigned short As[2][64 * RS];
    __shared__ __align__(16) unsigned short Bs[2][128 * RS];

    const int bx = blockIdx.x;
    const int nt = bx & 15, e = (bx >> 4) & 7, mt = bx >> 7;
    const int cnt = meta[e];
    const int m0 = mt * 64;
    if (m0 >= cnt) return;
    const int seg  = meta[8 + e];
    const int rows = min(64, cnt - m0);
    const int n0   = nt * 64;

    const int tid  = threadIdx.x;
    const int lane = tid & 63, wave = tid >> 6;
    const int quad = lane >> 4, l16 = lane & 15;
    const int wm = wave >> 1, wn = wave & 1;

    const float* __restrict__ Wb = gup + (size_t)e * (2 * IDIM * HDIM);

    // A staging: 64 rows x 32 fp32 = 512 float4 slots; 2 per thread.
    const float* aptr[2]; bool aval[2]; int aofs[2];
    #pragma unroll
    for (int c = 0; c < 2; ++c) {
        int id = tid + c * 256;
        int r = id >> 3, col = (id & 7) * 4;
        aval[c] = (r < rows);
        int tok = aval[c] ? (pairs[seg + m0 + r] >> 1) : 0;
        aptr[c] = hidden + (size_t)tok * HDIM + col;
        aofs[c] = r * RS + col;
    }
    // B staging: 128 weight rows (64 gate + 64 up) x 32 fp32; 4 float4/thread.
    const float* bptr[4]; int bofs[4];
    #pragma unroll
    for (int c = 0; c < 4; ++c) {
        int id = tid + c * 256;
        int r = id >> 3, col = (id & 7) * 4;
        int wr = (r < 64) ? (n0 + r) : (IDIM + n0 + (r - 64));
        bptr[c] = Wb + (size_t)wr * HDIM + col;
        bofs[c] = r * RS + col;
    }

    f32x4 accg[2][2], accu[2][2];
    const f32x4 zero = {0.f, 0.f, 0.f, 0.f};
    #pragma unroll
    for (int i = 0; i < 2; ++i)
        #pragma unroll
        for (int j = 0; j < 2; ++j) { accg[i][j] = zero; accu[i][j] = zero; }

    const float4 z4 = make_float4(0.f, 0.f, 0.f, 0.f);
    float4 Qa0[2], Qb0[4], Qa1[2], Qb1[4];   // two prefetch register sets

    auto load0 = [&](int k0) {
        #pragma unroll
        for (int c = 0; c < 2; ++c) Qa0[c] = aval[c] ? *(const float4*)(aptr[c] + k0) : z4;
        #pragma unroll
        for (int c = 0; c < 4; ++c) Qb0[c] = *(const float4*)(bptr[c] + k0);
    };
    auto load1 = [&](int k0) {
        #pragma unroll
        for (int c = 0; c < 2; ++c) Qa1[c] = aval[c] ? *(const float4*)(aptr[c] + k0) : z4;
        #pragma unroll
        for (int c = 0; c < 4; ++c) Qb1[c] = *(const float4*)(bptr[c] + k0);
    };
    auto store0 = [&](int buf) {
        #pragma unroll
        for (int c = 0; c < 2; ++c) st_bf4(&As[buf][aofs[c]], Qa0[c]);
        #pragma unroll
        for (int c = 0; c < 4; ++c) st_bf4(&Bs[buf][bofs[c]], Qb0[c]);
    };
    auto store1 = [&](int buf) {
        #pragma unroll
        for (int c = 0; c < 2; ++c) st_bf4(&As[buf][aofs[c]], Qa1[c]);
        #pragma unroll
        for (int c = 0; c < 4; ++c) st_bf4(&Bs[buf][bofs[c]], Qb1[c]);
    };
    auto compute = [&](int buf) {
        bf16x8 af[2], bg[2], bu[2];
        const int kq = quad * 8;
        #pragma unroll
        for (int i = 0; i < 2; ++i)
            af[i] = *(const bf16x8*)&As[buf][(wm * 32 + i * 16 + l16) * RS + kq];
        #pragma unroll
        for (int j = 0; j < 2; ++j) {
            bg[j] = *(const bf16x8*)&Bs[buf][(wn * 32 + j * 16 + l16) * RS + kq];
            bu[j] = *(const bf16x8*)&Bs[buf][(64 + wn * 32 + j * 16 + l16) * RS + kq];
        }
        #pragma unroll
        for (int i = 0; i < 2; ++i)
            #pragma unroll
            for (int j = 0; j < 2; ++j) {
                accg[i][j] = __builtin_amdgcn_mfma_f32_16x16x32_bf16(af[i], bg[j], accg[i][j], 0, 0, 0);
                accu[i][j] = __builtin_amdgcn_mfma_f32_16x16x32_bf16(af[i], bu[j], accu[i][j], 0, 0, 0);
            }
    };

    const int NK = HDIM / 32;   // 64 slabs
    // Prologue: slab0 -> LDS0; slab1 -> Q1; slab2 -> Q0.
    load0(0);
    store0(0);
    load1(32);
    load0(64);
    __syncthreads();

    for (int k = 0; ; k += 2) {
        compute(0);                           // slab k
        store1(1);                            // slab k+1 -> LDS1
        if (k + 3 < NK) load1((k + 3) * 32);  // slab k+3 -> Q1
        __syncthreads();
        compute(1);                           // slab k+1
        if (k + 2 >= NK) break;
        store0(0);                            // slab k+2 -> LDS0
        if (k + 4 < NK) load0((k + 4) * 32);  // slab k+4 -> Q0
        __syncthreads();
    }

    // Epilogue: inter[row][n] = silu(gate) * up, bf16.
    #pragma unroll
    for (int i = 0; i < 2; ++i) {
        #pragma unroll
        for (int r = 0; r < 4; ++r) {
            int ml = wm * 32 + i * 16 + quad * 4 + r;
            if (ml < rows) {
                size_t orow = (size_t)(seg + m0 + ml) * IDIM;
                #pragma unroll
                for (int j = 0; j < 2; ++j) {
                    int n = n0 + wn * 32 + j * 16 + l16;
                    float g = accg[i][j][r], u = accu[i][j][r];
                    float s = g * (1.f / (1.f + __expf(-g)));
                    inter[orow + n] = f2bf(s * u);
                }
            }
        }
    }
}

// ---------------------------------------------------------------------------
// Kernel 3: down-proj GEMM. Tile 64 rows x 64 cols, K=1024, depth-3 pipeline.
// Grid: mt(32) x e(8) x nt(32) = 8192; ~1024 active (4/CU).
// ---------------------------------------------------------------------------
__global__ __launch_bounds__(256, 4) void gemm2_down(
    const unsigned short* __restrict__ inter, const float* __restrict__ down,
    const int* __restrict__ meta, const int* __restrict__ pairs,
    float* __restrict__ out)
{
    __shared__ __align__(16) unsigned short As[2][64 * RS];
    __shared__ __align__(16) unsigned short Bs[2][64 * RS];

    const int bx = blockIdx.x;
    const int nt = bx & 31, e = (bx >> 5) & 7, mt = bx >> 8;
    const int cnt = meta[e];
    const int m0 = mt * 64;
    if (m0 >= cnt) return;
    const int seg  = meta[8 + e];
    const int rows = min(64, cnt - m0);
    const int n0   = nt * 64;

    const int tid  = threadIdx.x;
    const int lane = tid & 63, wave = tid >> 6;
    const int quad = lane >> 4, l16 = lane & 15;
    const int wm = wave >> 1, wn = wave & 1;

    const float* __restrict__ Db = down + (size_t)e * (HDIM * IDIM);

    // A staging: 64 rows x 32 bf16 = 256 x 16B chunks; 1 per thread.
    const int ar = tid >> 2, ako = (tid & 3) * 8;
    const bool aval = (ar < rows);
    const unsigned short* iptr = inter + (size_t)(seg + m0 + (aval ? ar : 0)) * IDIM + ako;
    const int aofs = ar * RS + ako;

    // B staging: 64 weight rows x 32 fp32 = 512 float4; 2 per thread.
    const float* bptr[2]; int bofs[2];
    #pragma unroll
    for (int c = 0; c < 2; ++c) {
        int id = tid + c * 256;
        int r = id >> 3, col = (id & 7) * 4;
        bptr[c] = Db + (size_t)(n0 + r) * IDIM + col;
        bofs[c] = r * RS + col;
    }

    f32x4 acc[2][2];
    const f32x4 zero = {0.f, 0.f, 0.f, 0.f};
    #pragma unroll
    for (int i = 0; i < 2; ++i)
        #pragma unroll
        for (int j = 0; j < 2; ++j) acc[i][j] = zero;

    const uint4 zu4 = make_uint4(0u, 0u, 0u, 0u);
    uint4 QaU0, QaU1; float4 Qb0[2], Qb1[2];

    auto load0 = [&](int k0) {
        QaU0 = aval ? *(const uint4*)(iptr + k0) : zu4;
        #pragma unroll
        for (int c = 0; c < 2; ++c) Qb0[c] = *(const float4*)(bptr[c] + k0);
    };
    auto load1 = [&](int k0) {
        QaU1 = aval ? *(const uint4*)(iptr + k0) : zu4;
        #pragma unroll
        for (int c = 0; c < 2; ++c) Qb1[c] = *(const float4*)(bptr[c] + k0);
    };
    auto store0 = [&](int buf) {
        *(uint4*)&As[buf][aofs] = QaU0;
        #pragma unroll
        for (int c = 0; c < 2; ++c) st_bf4(&Bs[buf][bofs[c]], Qb0[c]);
    };
    auto store1 = [&](int buf) {
        *(uint4*)&As[buf][aofs] = QaU1;
        #pragma unroll
        for (int c = 0; c < 2; ++c) st_bf4(&Bs[buf][bofs[c]], Qb1[c]);
    };
    auto compute = [&](int buf) {
        bf16x8 af[2], bf[2];
        const int kq = quad * 8;
        #pragma unroll
        for (int i = 0; i < 2; ++i)
            af[i] = *(const bf16x8*)&As[buf][(wm * 32 + i * 16 + l16) * RS + kq];
        #pragma unroll
        for (int j = 0; j < 2; ++j)
            bf[j] = *(const bf16x8*)&Bs[buf][(wn * 32 + j * 16 + l16) * RS + kq];
        #pragma unroll
        for (int i = 0; i < 2; ++i)
            #pragma unroll
            for (int j = 0; j < 2; ++j)
                acc[i][j] = __builtin_amdgcn_mfma_f32_16x16x32_bf16(af[i], bf[j], acc[i][j], 0, 0, 0);
    };

    const int NK = IDIM / 32;   // 32 slabs
    load0(0);
    store0(0);
    load1(32);
    load0(64);
    __syncthreads();

    for (int k = 0; ; k += 2) {
        compute(0);
        store1(1);
        if (k + 3 < NK) load1((k + 3) * 32);
        __syncthreads();
        compute(1);
        if (k + 2 >= NK) break;
        store0(0);
        if (k + 4 < NK) load0((k + 4) * 32);
        __syncthreads();
    }

    #pragma unroll
    for (int i = 0; i < 2; ++i) {
        #pragma unroll
        for (int r = 0; r < 4; ++r) {
            int ml = wm * 32 + i * 16 + quad * 4 + r;
            if (ml < rows) {
                int p = pairs[seg + m0 + ml];
                size_t ob = (size_t)p * HDIM + n0 + wn * 32 + l16;
                #pragma unroll
                for (int j = 0; j < 2; ++j)
                    out[ob + j * 16] = acc[i][j][r];
            }
        }
    }
}

// ---------------------------------------------------------------------------
extern "C" void kernel_launch(void* const* d_in, const int* in_sizes, int n_in,
                              void* d_out, int out_size, void* d_ws, size_t ws_size,
                              hipStream_t stream) {
    const float* hidden = (const float*)d_in[0];   // (T, H) fp32
    const int*   sel    = (const int*)  d_in[1];   // (T, K) int32
    const float* gup    = (const float*)d_in[2];   // (E, 2I, H) fp32
    const float* down   = (const float*)d_in[3];   // (E, H, I) fp32
    float* out = (float*)d_out;                    // (T, K, H) fp32

    int* meta  = (int*)d_ws;                       // 16 ints: cnt[8], start[8]
    int* pairs = meta + 16;                        // 2048 ints
    unsigned short* inter = (unsigned short*)((char*)d_ws + 16384); // 2048 x 1024 bf16 (4 MB)

    build_pairs<<<1, 256, 0, stream>>>(sel, meta, pairs);
    gemm1_gateup<<<4096, 256, 0, stream>>>(hidden, gup, meta, pairs, inter);
    gemm2_down  <<<8192, 256, 0, stream>>>(inter, down, meta, pairs, out);
}